// Round 6
// baseline (10436.858 us; speedup 1.0000x reference)
//
#include <hip/hip_runtime.h>
#include <math.h>
#include <stdint.h>

#define B 128
#define S 512
#define V 6000
#define E 100
#define H 256
#define G4 1024   /* 4*H */
#define T 9

/* W column split (float4 k-groups, 64 total = 256 cols per row)
   R6: same group->resource map as the verified R0 anchor
   (0..19 pin/direct, 20..22 LDS slab, 23..63 prepacked stream; k_prep and
   workspace overlay byte-identical), but the WORK is k-split 2-ways:
   thread (u = t&255, half = t>>8) owns all 4 gate rows of unit u over
   k-groups [half*32, half*32+32). Each hs4 broadcast now feeds 16 FMA
   (was 8) -> per-wave hs reads 64->32, cutting the contended LDS pipe
   ~30%/step (R5 lesson: LDS pipe, not L2 bytes, is the binding term). */
#define WREG 20            /* groups [0,20): pin (first 10) + direct reload */
#define WLDS 3             /* groups [20,23): 48 KB LDS slab */
#define WSTR 41            /* groups [23,64): prepacked k-major stream */

/* workspace byte offsets (256-aligned) */
#define OFF_PEMB_F 0u
#define PEMB_BYTES (V*G4*4u)                    /* 24,576,000 */
#define OFF_PEMB_B (OFF_PEMB_F + PEMB_BYTES)
#define OFF_EMF    (OFF_PEMB_B + PEMB_BYTES)    /* 49,152,000 */
#define EM_BYTES   (B*S*T*4u)                   /* 2,359,296 */
#define OFF_EMB    (OFF_EMF + EM_BYTES)
#define OFF_BP     (OFF_EMB + EM_BYTES)         /* 53,870,592 */
#define BP_BYTES   ((S-1)*B*16u)                /* 1,046,528 */
#define OFF_LT     (OFF_BP + BP_BYTES)
#define OFF_PT     (OFF_LT + 512u)
/* Streamed-W (2 dirs x 41 groups x 1024 rows x 16 B = 1,343,488 B) OVERLAYS
   the BP/LT/PT region: k_prep writes it and k_lstm reads it strictly BEFORE
   k_vit/k_back write BP/LT/PT (stream-ordered). R0 proved this footprint. */
#define OFF_WSTREAM OFF_BP

__device__ __forceinline__ float sigf(float x) { return 1.0f / (1.0f + expf(-x)); }

/* pemb[v][g4] = bias[g4] + sum_e emb[v][e] * W_ih[g4][e],  g4 = q*H + j */
__global__ __launch_bounds__(256) void k_pemb(const float* __restrict__ emb,
                                              const float* __restrict__ wf, const float* __restrict__ bf,
                                              const float* __restrict__ wb, const float* __restrict__ bb,
                                              char* __restrict__ ws) {
    int blk = blockIdx.x;                   /* 0..749 */
    int d   = blk >= 375;
    int vb  = d ? blk - 375 : blk;
    const float* W    = d ? wb : wf;
    const float* bias = d ? bb : bf;
    float* pe = (float*)(ws + (d ? OFF_PEMB_B : OFF_PEMB_F));

    __shared__ float es[16 * E];
    for (int i = threadIdx.x; i < 16 * E; i += 256) es[i] = emb[vb * 16 * E + i];
    __syncthreads();

    int j = threadIdx.x;
    float acc[4][16];
    #pragma unroll
    for (int q = 0; q < 4; q++) {
        float bq = bias[q * H + j];
        #pragma unroll
        for (int v = 0; v < 16; v++) acc[q][v] = bq;
    }
    for (int e = 0; e < E; e++) {
        float w0 = W[(0 * H + j) * E + e];
        float w1 = W[(1 * H + j) * E + e];
        float w2 = W[(2 * H + j) * E + e];
        float w3 = W[(3 * H + j) * E + e];
        #pragma unroll
        for (int v = 0; v < 16; v++) {
            float x = es[v * E + e];
            acc[0][v] += w0 * x; acc[1][v] += w1 * x;
            acc[2][v] += w2 * x; acc[3][v] += w3 * x;
        }
    }
    for (int v = 0; v < 16; v++)
        #pragma unroll
        for (int q = 0; q < 4; q++)
            pe[(vb * 16 + v) * G4 + q * H + j] = acc[q][v];
}

/* streamed-W layout: wstr[(d*WSTR + g)*1024 + r] = {W_d[r][92+4g .. +3]}
   -> per step, lane r loads consecutive float4 (coalesced 1 KB/wave-inst) */
__global__ __launch_bounds__(256) void k_prep(const float* __restrict__ whhf,
                                              const float* __restrict__ whhb,
                                              char* __restrict__ ws) {
    int tid = blockIdx.x * 256 + threadIdx.x;   /* 2*41*1024 = 83968 */
    if (tid >= 2 * WSTR * 1024) return;
    int d   = tid >= WSTR * 1024;
    int idx = d ? tid - WSTR * 1024 : tid;
    int g = idx >> 10, r = idx & 1023;
    const float* whh = d ? whhb : whhf;
    float4* wstr = (float4*)(ws + OFF_WSTREAM);
    const float4* src = (const float4*)(whh + (size_t)r * H + 4 * (WREG + WLDS));
    wstr[((size_t)(d * WSTR + g) << 10) + r] = src[g];
}

/* R6 k_lstm: 256 blocks (dir d = blk>>7, batch b = blk&127) x 512 thr
   (2 waves/SIMD). k-split 2-ways: thread (u,half) computes all 4 gates of
   unit u over k-groups [half*32, (half+1)*32). Halves exchange 4 partials
   via pbuf at the existing B1 barrier (gbuf eliminated). */
__global__ __attribute__((amdgpu_flat_work_group_size(512, 512), amdgpu_waves_per_eu(2, 2)))
void k_lstm(const int* __restrict__ data,
            const float* __restrict__ whhf,
            const float* __restrict__ whhb,
            const float* __restrict__ mlpW,
            char* __restrict__ ws) {
    int blk = blockIdx.x;
    int d = blk >> 7, b = blk & 127;
    const float* whh = d ? whhb : whhf;
    const float* pe  = (const float*)(ws + (d ? OFF_PEMB_B : OFF_PEMB_F));
    float* emdst = (float*)(ws + (d ? OFF_EMB : OFF_EMF));
    const float4* wstr = (const float4*)(ws + OFF_WSTREAM) + ((size_t)(d * WSTR) << 10);

    __shared__ __align__(16) float hs[H];          /* h_prev, 1 KB */
    __shared__ float4 sW[WLDS << 10];              /* 48 KB: groups 20..22 */
    __shared__ __align__(16) float4 pbuf[2][256];  /* 8 KB partial gates */
    __shared__ float  red[T][4];
    __shared__ int    toks[S];                     /* 2 KB */

    int t = threadIdx.x;                       /* 0..511 */
    int u = t & 255, half = t >> 8;

    const float4* wr0 = (const float4*)(whh + (size_t)(u      ) * H);
    const float4* wr1 = (const float4*)(whh + (size_t)(u + 256) * H);
    const float4* wr2 = (const float4*)(whh + (size_t)(u + 512) * H);
    const float4* wr3 = (const float4*)(whh + (size_t)(u + 768) * H);

    /* pinned set: groups 0..9 x 4 rows (160 floats). At 2 waves/SIMD the
       budget is 256 VGPR; live estimate ~210 fits. If the allocator remats
       instead, behavior degrades to R0's (still fine). */
    float4 wPa[10], wPb[10], wPc[10], wPd[10];
    #pragma unroll
    for (int g = 0; g < 10; g++) {
        wPa[g] = wr0[g]; wPb[g] = wr1[g]; wPc[g] = wr2[g]; wPd[g] = wr3[g];
    }
    #pragma unroll
    for (int g = 0; g < 10; g++) {
        asm volatile("" : "+v"(wPa[g].x), "+v"(wPa[g].y), "+v"(wPa[g].z), "+v"(wPa[g].w));
        asm volatile("" : "+v"(wPb[g].x), "+v"(wPb[g].y), "+v"(wPb[g].z), "+v"(wPb[g].w));
        asm volatile("" : "+v"(wPc[g].x), "+v"(wPc[g].y), "+v"(wPc[g].z), "+v"(wPc[g].w));
        asm volatile("" : "+v"(wPd[g].x), "+v"(wPd[g].y), "+v"(wPd[g].z), "+v"(wPd[g].w));
    }

    /* stage sW: groups 20..22 for all 1024 rows (one-time) */
    for (int i = t; i < (WLDS << 10); i += 512) {
        int g = i >> 10, r = i & 1023;
        sW[i] = ((const float4*)(whh + (size_t)r * H))[WREG + g];
    }

    toks[t] = data[b * S + t];                 /* S == 512 == blockDim */

    float mw[T];
    if (t < 256) {
        #pragma unroll
        for (int tt = 0; tt < T; tt++) mw[tt] = mlpW[tt * (2 * H) + d * H + t];
    }
    if (t < H) hs[t] = 0.0f;
    float cst = 0.0f;
    __syncthreads();

    const float4* hs4 = (const float4*)hs;

    float pf0 = 0.0f, pf1 = 0.0f, pf2 = 0.0f, pf3 = 0.0f;
    if (half == 0) {
        int sp0 = d ? (S - 1) : 0;
        size_t tok = (size_t)toks[sp0];
        pf0 = pe[(tok << 10) + u];
        pf1 = pe[(tok << 10) + u + 256];
        pf2 = pe[(tok << 10) + u + 512];
        pf3 = pe[(tok << 10) + u + 768];
    }

    for (int ss = 0; ss < S; ss++) {
        int sp = d ? (S - 1 - ss) : ss;
        float a0, a1, a2, a3;
        if (half == 0) { a0 = pf0; a1 = pf1; a2 = pf2; a3 = pf3; }
        else           { a0 = a1 = a2 = a3 = 0.0f; }

        if (half == 0 && ss + 1 < S) {
            int spn = d ? (S - 2 - ss) : (ss + 1);
            size_t tok = (size_t)toks[spn];
            pf0 = pe[(tok << 10) + u];
            pf1 = pe[(tok << 10) + u + 256];
            pf2 = pe[(tok << 10) + u + 512];
            pf3 = pe[(tok << 10) + u + 768];
        }

        if (half == 0) {
            /* A1: pinned groups 0..9 */
            #pragma unroll
            for (int g = 0; g < 10; g++) {
                float4 h4 = hs4[g];
                a0 = fmaf(wPa[g].x, h4.x, a0);  a1 = fmaf(wPb[g].x, h4.x, a1);
                a2 = fmaf(wPc[g].x, h4.x, a2);  a3 = fmaf(wPd[g].x, h4.x, a3);
                a0 = fmaf(wPa[g].y, h4.y, a0);  a1 = fmaf(wPb[g].y, h4.y, a1);
                a2 = fmaf(wPc[g].y, h4.y, a2);  a3 = fmaf(wPd[g].y, h4.y, a3);
                a0 = fmaf(wPa[g].z, h4.z, a0);  a1 = fmaf(wPb[g].z, h4.z, a1);
                a2 = fmaf(wPc[g].z, h4.z, a2);  a3 = fmaf(wPd[g].z, h4.z, a3);
                a0 = fmaf(wPa[g].w, h4.w, a0);  a1 = fmaf(wPb[g].w, h4.w, a1);
                a2 = fmaf(wPc[g].w, h4.w, a2);  a3 = fmaf(wPd[g].w, h4.w, a3);
            }
            /* A2: direct reload groups 10..19 */
            #pragma unroll
            for (int g = 10; g < WREG; g++) {
                float4 h4 = hs4[g];
                float4 w0 = wr0[g], w1 = wr1[g], w2 = wr2[g], w3 = wr3[g];
                a0 = fmaf(w0.x, h4.x, a0);  a1 = fmaf(w1.x, h4.x, a1);
                a2 = fmaf(w2.x, h4.x, a2);  a3 = fmaf(w3.x, h4.x, a3);
                a0 = fmaf(w0.y, h4.y, a0);  a1 = fmaf(w1.y, h4.y, a1);
                a2 = fmaf(w2.y, h4.y, a2);  a3 = fmaf(w3.y, h4.y, a3);
                a0 = fmaf(w0.z, h4.z, a0);  a1 = fmaf(w1.z, h4.z, a1);
                a2 = fmaf(w2.z, h4.z, a2);  a3 = fmaf(w3.z, h4.z, a3);
                a0 = fmaf(w0.w, h4.w, a0);  a1 = fmaf(w1.w, h4.w, a1);
                a2 = fmaf(w2.w, h4.w, a2);  a3 = fmaf(w3.w, h4.w, a3);
            }
            /* B: LDS slab groups 20..22 */
            #pragma unroll
            for (int g = 0; g < WLDS; g++) {
                float4 h4 = hs4[WREG + g];
                float4 w0 = sW[(g << 10) + u      ];
                float4 w1 = sW[(g << 10) + u + 256];
                float4 w2 = sW[(g << 10) + u + 512];
                float4 w3 = sW[(g << 10) + u + 768];
                a0 = fmaf(w0.x, h4.x, a0);  a1 = fmaf(w1.x, h4.x, a1);
                a2 = fmaf(w2.x, h4.x, a2);  a3 = fmaf(w3.x, h4.x, a3);
                a0 = fmaf(w0.y, h4.y, a0);  a1 = fmaf(w1.y, h4.y, a1);
                a2 = fmaf(w2.y, h4.y, a2);  a3 = fmaf(w3.y, h4.y, a3);
                a0 = fmaf(w0.z, h4.z, a0);  a1 = fmaf(w1.z, h4.z, a1);
                a2 = fmaf(w2.z, h4.z, a2);  a3 = fmaf(w3.z, h4.z, a3);
                a0 = fmaf(w0.w, h4.w, a0);  a1 = fmaf(w1.w, h4.w, a1);
                a2 = fmaf(w2.w, h4.w, a2);  a3 = fmaf(w3.w, h4.w, a3);
            }
            /* C: stream groups 23..31 (wstr slots 0..8) */
            #pragma unroll 3
            for (int g = 0; g < 9; g++) {
                float4 h4 = hs4[WREG + WLDS + g];
                const float4* wg = wstr + ((size_t)g << 10) + u;
                float4 w0 = wg[0], w1 = wg[256], w2 = wg[512], w3 = wg[768];
                a0 = fmaf(w0.x, h4.x, a0);  a1 = fmaf(w1.x, h4.x, a1);
                a2 = fmaf(w2.x, h4.x, a2);  a3 = fmaf(w3.x, h4.x, a3);
                a0 = fmaf(w0.y, h4.y, a0);  a1 = fmaf(w1.y, h4.y, a1);
                a2 = fmaf(w2.y, h4.y, a2);  a3 = fmaf(w3.y, h4.y, a3);
                a0 = fmaf(w0.z, h4.z, a0);  a1 = fmaf(w1.z, h4.z, a1);
                a2 = fmaf(w2.z, h4.z, a2);  a3 = fmaf(w3.z, h4.z, a3);
                a0 = fmaf(w0.w, h4.w, a0);  a1 = fmaf(w1.w, h4.w, a1);
                a2 = fmaf(w2.w, h4.w, a2);  a3 = fmaf(w3.w, h4.w, a3);
            }
        } else {
            /* D: stream groups 32..63 (wstr slots 9..40) */
            #pragma unroll 4
            for (int g = 0; g < 32; g++) {
                float4 h4 = hs4[32 + g];
                const float4* wg = wstr + ((size_t)(9 + g) << 10) + u;
                float4 w0 = wg[0], w1 = wg[256], w2 = wg[512], w3 = wg[768];
                a0 = fmaf(w0.x, h4.x, a0);  a1 = fmaf(w1.x, h4.x, a1);
                a2 = fmaf(w2.x, h4.x, a2);  a3 = fmaf(w3.x, h4.x, a3);
                a0 = fmaf(w0.y, h4.y, a0);  a1 = fmaf(w1.y, h4.y, a1);
                a2 = fmaf(w2.y, h4.y, a2);  a3 = fmaf(w3.y, h4.y, a3);
                a0 = fmaf(w0.z, h4.z, a0);  a1 = fmaf(w1.z, h4.z, a1);
                a2 = fmaf(w2.z, h4.z, a2);  a3 = fmaf(w3.z, h4.z, a3);
                a0 = fmaf(w0.w, h4.w, a0);  a1 = fmaf(w1.w, h4.w, a1);
                a2 = fmaf(w2.w, h4.w, a2);  a3 = fmaf(w3.w, h4.w, a3);
            }
        }

        pbuf[half][u] = make_float4(a0, a1, a2, a3);
        __syncthreads();   /* B1: partials complete, hs reads done */

        if (t < 256) {
            float4 pa = pbuf[0][t], pb = pbuf[1][t];
            float ig = sigf(pa.x + pb.x), fg = sigf(pa.y + pb.y);
            float tg = tanhf(pa.z + pb.z), og = sigf(pa.w + pb.w);
            cst = fg * cst + ig * tg;
            float hn = og * tanhf(cst);
            hs[t] = hn;
            int l = t & 63, wv = t >> 6;
            #pragma unroll
            for (int tt = 0; tt < T; tt++) {
                float v = hn * mw[tt];
                v += __shfl_xor(v, 32, 64); v += __shfl_xor(v, 16, 64);
                v += __shfl_xor(v, 8, 64);  v += __shfl_xor(v, 4, 64);
                v += __shfl_xor(v, 2, 64);  v += __shfl_xor(v, 1, 64);
                if (l == 0) red[tt][wv] = v;
            }
        }
        __syncthreads();   /* B2: hs updated + red ready */
        if (t < T)
            emdst[((size_t)b * S + sp) * T + t] = red[t][0] + red[t][1] + red[t][2] + red[t][3];
    }
}

/* Viterbi forward: one wave per batch, lane t = tag. Strict-> ascending scan
   matches jnp.argmax first-index tie-breaking. */
__global__ __launch_bounds__(64) void k_vit(const int* __restrict__ data,
                                            const float* __restrict__ strans,
                                            const float* __restrict__ trans,
                                            const float* __restrict__ etrans,
                                            const float* __restrict__ mlpb,
                                            float* __restrict__ out,
                                            char* __restrict__ ws) {
    int b = blockIdx.x, t = threadIdx.x;
    const float* emf = (const float*)(ws + OFF_EMF);
    const float* emb = (const float*)(ws + OFF_EMB);
    char* bp = ws + OFF_BP;
    int*  lt = (int*)(ws + OFF_LT);
    bool act = t < T;

    float trp[T];
    float mb = 0.0f;
    if (act) {
        #pragma unroll
        for (int p = 0; p < T; p++) trp[p] = trans[p * T + t];
        mb = mlpb[t];
    }
    float score = -1e30f;
    if (act) score = strans[t] + emf[(b * S) * T + t] + emb[(b * S) * T + t] + mb;

    for (int s = 1; s < S; s++) {
        float e = 0.0f;
        if (act) e = emf[(b * S + s) * T + t] + emb[(b * S + s) * T + t] + mb;
        float best = __shfl(score, 0, 64) + trp[0];
        int bpi = 0;
        #pragma unroll
        for (int p = 1; p < T; p++) {
            float cand = __shfl(score, p, 64) + trp[p];
            if (cand > best) { best = cand; bpi = p; }
        }
        int m = data[b * S + s] != 0;
        if (act) {
            score = m ? (best + e) : score;
            bp[((size_t)(s - 1) * B + b) * 16 + t] = (char)bpi;
        }
    }
    float fin = act ? score + etrans[t] : -1e30f;
    float bv = __shfl(fin, 0, 64);
    int bi = 0;
    #pragma unroll
    for (int p = 1; p < T; p++) {
        float v = __shfl(fin, p, 64);
        if (v > bv) { bv = v; bi = p; }
    }
    if (t == 0) { out[B * S + b] = bv; lt[b] = bi; }
}

/* Backtrack: thread = batch; bp row address is tag-independent -> pipelined loads */
__global__ __launch_bounds__(128) void k_back(const int* __restrict__ data, char* __restrict__ ws) {
    int b = threadIdx.x;
    const int4* bp4 = (const int4*)(ws + OFF_BP);
    const int*  lt  = (const int*)(ws + OFF_LT);
    int* pt = (int*)(ws + OFF_PT);
    int tag = lt[b];
    pt[(S - 1) * B + b] = tag;
    for (int p = S - 2; p >= 0; p--) {
        int4 r = bp4[(size_t)p * B + b];
        int m = data[b * S + p + 1] != 0;
        unsigned w = (unsigned)(tag < 8 ? (tag < 4 ? r.x : r.y) : r.z);
        int nt = (int)((w >> ((tag & 3) * 8)) & 0xff);
        tag = m ? nt : tag;
        pt[p * B + b] = tag;
    }
}

/* paths -> float output with mask zeroing */
__global__ __launch_bounds__(256) void k_fin(const int* __restrict__ data,
                                             float* __restrict__ out,
                                             const char* __restrict__ ws) {
    int tid = blockIdx.x * 256 + threadIdx.x;   /* 65536 */
    const int* pt = (const int*)(ws + OFF_PT);
    int b = tid >> 9, p = tid & 511;
    out[tid] = (data[tid] != 0) ? (float)pt[p * B + b] : 0.0f;
}

extern "C" void kernel_launch(void* const* d_in, const int* in_sizes, int n_in,
                              void* d_out, int out_size, void* d_ws, size_t ws_size,
                              hipStream_t stream) {
    const int*   data = (const int*)d_in[0];
    /* d_in[1] = mask (bool) — unused; mask == (data != 0) */
    const float* emb  = (const float*)d_in[2];
    const float* wihf = (const float*)d_in[3];
    const float* whhf = (const float*)d_in[4];
    const float* bf   = (const float*)d_in[5];
    const float* wihb = (const float*)d_in[6];
    const float* whhb = (const float*)d_in[7];
    const float* bb   = (const float*)d_in[8];
    const float* mlpW = (const float*)d_in[9];
    const float* mlpb = (const float*)d_in[10];
    const float* st   = (const float*)d_in[11];
    const float* tr   = (const float*)d_in[12];
    const float* et   = (const float*)d_in[13];
    float* out = (float*)d_out;
    char*  ws  = (char*)d_ws;

    hipLaunchKernelGGL(k_pemb, dim3(750),  dim3(256), 0, stream, emb, wihf, bf, wihb, bb, ws);
    hipLaunchKernelGGL(k_prep, dim3(328),  dim3(256), 0, stream, whhf, whhb, ws);
    hipLaunchKernelGGL(k_lstm, dim3(256),  dim3(512), 0, stream, data, whhf, whhb, mlpW, ws);
    hipLaunchKernelGGL(k_vit,  dim3(128),  dim3(64),  0, stream, data, st, tr, et, mlpb, out, ws);
    hipLaunchKernelGGL(k_back, dim3(1),    dim3(128), 0, stream, data, ws);
    hipLaunchKernelGGL(k_fin,  dim3(256),  dim3(256), 0, stream, data, out, ws);
}

// Round 7
// 4166.610 us; speedup vs baseline: 2.5049x; 2.5049x over previous
//
#include <hip/hip_runtime.h>
#include <math.h>
#include <stdint.h>

#define B 128
#define S 512
#define V 6000
#define E 100
#define H 256
#define G4 1024   /* 4*H */
#define T 9

/* W column split (float4 k-groups, 64 total = 256 cols per row)
   R7 = R0 anchor exactly (20/3/41, asm-pin, 2-row/thread, 2 waves/SIMD).
   Change: emission reduction moved OFF the B1->B2 critical section onto
   threads 256..399 (idle there in R0), reading hs after B2. */
#define WREG 20            /* cols [0,80)  "pinned": forces ~160 live load results
                              = deep load pipeline (prev-session R9/R13 win) */
#define WLDS 3             /* cols [80,92) in LDS slab (48 KB) */
#define WSTR 41            /* cols [92,256) streamed k-major (656 KB/step/dir) */

/* workspace byte offsets (256-aligned) */
#define OFF_PEMB_F 0u
#define PEMB_BYTES (V*G4*4u)                    /* 24,576,000 */
#define OFF_PEMB_B (OFF_PEMB_F + PEMB_BYTES)
#define OFF_EMF    (OFF_PEMB_B + PEMB_BYTES)    /* 49,152,000 */
#define EM_BYTES   (B*S*T*4u)                   /* 2,359,296 */
#define OFF_EMB    (OFF_EMF + EM_BYTES)
#define OFF_BP     (OFF_EMB + EM_BYTES)         /* 53,870,592 */
#define BP_BYTES   ((S-1)*B*16u)                /* 1,046,528 */
#define OFF_LT     (OFF_BP + BP_BYTES)
#define OFF_PT     (OFF_LT + 512u)
/* Streamed-W (2 dirs x 41 groups x 1024 rows x 16 B = 1,343,488 B) OVERLAYS
   the BP/LT/PT region: k_prep writes it and k_lstm reads it strictly BEFORE
   k_vit/k_back write BP/LT/PT (stream-ordered). */
#define OFF_WSTREAM OFF_BP

__device__ __forceinline__ float sigf(float x) { return 1.0f / (1.0f + expf(-x)); }

/* pemb[v][g4] = bias[g4] + sum_e emb[v][e] * W_ih[g4][e],  g4 = q*H + j */
__global__ __launch_bounds__(256) void k_pemb(const float* __restrict__ emb,
                                              const float* __restrict__ wf, const float* __restrict__ bf,
                                              const float* __restrict__ wb, const float* __restrict__ bb,
                                              char* __restrict__ ws) {
    int blk = blockIdx.x;                   /* 0..749 */
    int d   = blk >= 375;
    int vb  = d ? blk - 375 : blk;
    const float* W    = d ? wb : wf;
    const float* bias = d ? bb : bf;
    float* pe = (float*)(ws + (d ? OFF_PEMB_B : OFF_PEMB_F));

    __shared__ float es[16 * E];
    for (int i = threadIdx.x; i < 16 * E; i += 256) es[i] = emb[vb * 16 * E + i];
    __syncthreads();

    int j = threadIdx.x;
    float acc[4][16];
    #pragma unroll
    for (int q = 0; q < 4; q++) {
        float bq = bias[q * H + j];
        #pragma unroll
        for (int v = 0; v < 16; v++) acc[q][v] = bq;
    }
    for (int e = 0; e < E; e++) {
        float w0 = W[(0 * H + j) * E + e];
        float w1 = W[(1 * H + j) * E + e];
        float w2 = W[(2 * H + j) * E + e];
        float w3 = W[(3 * H + j) * E + e];
        #pragma unroll
        for (int v = 0; v < 16; v++) {
            float x = es[v * E + e];
            acc[0][v] += w0 * x; acc[1][v] += w1 * x;
            acc[2][v] += w2 * x; acc[3][v] += w3 * x;
        }
    }
    for (int v = 0; v < 16; v++)
        #pragma unroll
        for (int q = 0; q < 4; q++)
            pe[(vb * 16 + v) * G4 + q * H + j] = acc[q][v];
}

/* streamed-W layout: wstr[(d*WSTR + g)*1024 + r] = {W_d[r][92+4g .. +3]}
   -> per step, lane r loads consecutive float4 (coalesced 1 KB/wave-inst) */
__global__ __launch_bounds__(256) void k_prep(const float* __restrict__ whhf,
                                              const float* __restrict__ whhb,
                                              char* __restrict__ ws) {
    int tid = blockIdx.x * 256 + threadIdx.x;   /* 2*41*1024 = 83968 */
    if (tid >= 2 * WSTR * 1024) return;
    int d   = tid >= WSTR * 1024;
    int idx = d ? tid - WSTR * 1024 : tid;
    int g = idx >> 10, r = idx & 1023;
    const float* whh = d ? whhb : whhf;
    float4* wstr = (float4*)(ws + OFF_WSTREAM);
    const float4* src = (const float4*)(whh + (size_t)r * H + 4 * (WREG + WLDS));
    wstr[((size_t)(d * WSTR + g) << 10) + r] = src[g];
}

/* Single-CU LSTM: 256 blocks (dir d = blk>>7, batch b = blk&127) x 512 thr.
   Thread t owns gate rows t and t+512. Per row: cols [0,80) asm-pinned loads
   (deep load pipeline), [80,92) in LDS, [92,256) streamed coalesced from L2.
   R7: emission dot-products computed by threads 256..399 AFTER B2 (reading
   hs), overlapping the next step's matvec of waves 0-3 instead of sitting
   inside the B1->B2 serial section. red[] deleted; barriers unchanged. */
__global__ __attribute__((amdgpu_flat_work_group_size(512, 512), amdgpu_waves_per_eu(2, 2)))
void k_lstm(const int* __restrict__ data,
            const float* __restrict__ whhf,
            const float* __restrict__ whhb,
            const float* __restrict__ mlpW,
            char* __restrict__ ws) {
    int blk = blockIdx.x;
    int d = blk >> 7, b = blk & 127;
    const float* whh = d ? whhb : whhf;
    const float* pe  = (const float*)(ws + (d ? OFF_PEMB_B : OFF_PEMB_F));
    float* emdst = (float*)(ws + (d ? OFF_EMB : OFF_EMF));
    const float4* wstr = (const float4*)(ws + OFF_WSTREAM) + ((size_t)(d * WSTR) << 10);

    __shared__ __align__(16) float hs[H];      /* h_prev, 1 KB */
    __shared__ float4 sW[WLDS << 10];          /* 48 KB */
    __shared__ float  gbuf[G4];                /* 4 KB */
    __shared__ int    toks[S];                 /* 2 KB */

    int t = threadIdx.x;                       /* 0..511 */
    int r0 = t, r1 = t + 512;

    const float4* wrow0 = (const float4*)(whh + (size_t)r0 * H);
    const float4* wrow1 = (const float4*)(whh + (size_t)r1 * H);
    float4 wA[WREG], wB[WREG];
    #pragma unroll
    for (int g = 0; g < WREG; g++) { wA[g] = wrow0[g]; wB[g] = wrow1[g]; }
    /* pin: consume the loads pre-loop; keeps a ~160-reg load pipeline live */
    #pragma unroll
    for (int g = 0; g < WREG; g++) {
        asm volatile("" : "+v"(wA[g].x), "+v"(wA[g].y), "+v"(wA[g].z), "+v"(wA[g].w));
        asm volatile("" : "+v"(wB[g].x), "+v"(wB[g].y), "+v"(wB[g].z), "+v"(wB[g].w));
    }
    #pragma unroll
    for (int g = 0; g < WLDS; g++) {
        sW[(g << 10) + r0] = wrow0[WREG + g];
        sW[(g << 10) + r1] = wrow1[WREG + g];
    }

    toks[t] = data[b * S + t];                 /* S == 512 == blockDim */

    /* emission operands: threads 256..399 = tag tt, slice l */
    float mwE[16];
    int tt = (t - 256) >> 4, el = (t - 256) & 15;
    if (t >= 256 && t < 256 + 16 * T) {
        #pragma unroll
        for (int k = 0; k < 16; k++)
            mwE[k] = mlpW[tt * (2 * H) + d * H + el + 16 * k];
    }
    if (t < H) hs[t] = 0.0f;
    float cst = 0.0f;
    __syncthreads();

    const float4* hs4 = (const float4*)hs;
    const float4* wsp0 = wstr + r0;
    const float4* wsp1 = wstr + r1;

    float pf0, pf1;
    {
        int sp0 = d ? (S - 1) : 0;
        size_t tok = (size_t)toks[sp0];
        pf0 = pe[(tok << 10) + r0];
        pf1 = pe[(tok << 10) + r1];
    }

    for (int ss = 0; ss < S; ss++) {
        int sp = d ? (S - 1 - ss) : ss;
        float acc0 = pf0, acc1 = pf1;
        if (ss + 1 < S) {
            int spn = d ? (S - 2 - ss) : (ss + 1);
            size_t tok = (size_t)toks[spn];
            pf0 = pe[(tok << 10) + r0];
            pf1 = pe[(tok << 10) + r1];
        }

        /* "register"-W phase: cols 0..79 */
        #pragma unroll
        for (int g = 0; g < WREG; g++) {
            float4 h4 = hs4[g];
            float4 a = wA[g], bb2 = wB[g];
            acc0 = fmaf(a.x, h4.x, acc0);  acc1 = fmaf(bb2.x, h4.x, acc1);
            acc0 = fmaf(a.y, h4.y, acc0);  acc1 = fmaf(bb2.y, h4.y, acc1);
            acc0 = fmaf(a.z, h4.z, acc0);  acc1 = fmaf(bb2.z, h4.z, acc1);
            acc0 = fmaf(a.w, h4.w, acc0);  acc1 = fmaf(bb2.w, h4.w, acc1);
        }
        /* LDS-W phase: cols 80..91 */
        #pragma unroll
        for (int g = 0; g < WLDS; g++) {
            float4 w0 = sW[(g << 10) + r0];
            float4 w1 = sW[(g << 10) + r1];
            float4 h4 = hs4[WREG + g];
            acc0 = fmaf(w0.x, h4.x, acc0);  acc1 = fmaf(w1.x, h4.x, acc1);
            acc0 = fmaf(w0.y, h4.y, acc0);  acc1 = fmaf(w1.y, h4.y, acc1);
            acc0 = fmaf(w0.z, h4.z, acc0);  acc1 = fmaf(w1.z, h4.z, acc1);
            acc0 = fmaf(w0.w, h4.w, acc0);  acc1 = fmaf(w1.w, h4.w, acc1);
        }
        /* streamed phase: cols 92..255 (bounded pipelining via unroll 4) */
        #pragma unroll 4
        for (int g = 0; g < WSTR; g++) {
            float4 w0 = wsp0[(size_t)g << 10];
            float4 w1 = wsp1[(size_t)g << 10];
            float4 h4 = hs4[WREG + WLDS + g];
            acc0 = fmaf(w0.x, h4.x, acc0);  acc1 = fmaf(w1.x, h4.x, acc1);
            acc0 = fmaf(w0.y, h4.y, acc0);  acc1 = fmaf(w1.y, h4.y, acc1);
            acc0 = fmaf(w0.z, h4.z, acc0);  acc1 = fmaf(w1.z, h4.z, acc1);
            acc0 = fmaf(w0.w, h4.w, acc0);  acc1 = fmaf(w1.w, h4.w, acc1);
        }
        gbuf[r0] = acc0;
        gbuf[r1] = acc1;
        __syncthreads();   /* B1: gates complete, hs reads done */

        if (t < 256) {
            float gi = gbuf[t], gf = gbuf[H + t], gg = gbuf[2 * H + t], go = gbuf[3 * H + t];
            float ig = sigf(gi), fg = sigf(gf), tg = tanhf(gg), og = sigf(go);
            cst = fg * cst + ig * tg;
            float hn = og * tanhf(cst);
            hs[t] = hn;
        }
        __syncthreads();   /* B2: hs updated */

        /* emission on otherwise-idle threads 256..399, overlapping the
           next matvec of waves 0-3. Reads hs (published by B2); finishes
           before these waves reach next B1, which gates the next hs write. */
        if (t >= 256 && t < 256 + 16 * T) {
            float v = 0.0f;
            #pragma unroll
            for (int k = 0; k < 16; k++) v = fmaf(hs[el + 16 * k], mwE[k], v);
            v += __shfl_xor(v, 8, 16);
            v += __shfl_xor(v, 4, 16);
            v += __shfl_xor(v, 2, 16);
            v += __shfl_xor(v, 1, 16);
            if (el == 0)
                emdst[((size_t)b * S + sp) * T + tt] = v;
        }
    }
}

/* Viterbi forward: one wave per batch, lane t = tag. Strict-> ascending scan
   matches jnp.argmax first-index tie-breaking. */
__global__ __launch_bounds__(64) void k_vit(const int* __restrict__ data,
                                            const float* __restrict__ strans,
                                            const float* __restrict__ trans,
                                            const float* __restrict__ etrans,
                                            const float* __restrict__ mlpb,
                                            float* __restrict__ out,
                                            char* __restrict__ ws) {
    int b = blockIdx.x, t = threadIdx.x;
    const float* emf = (const float*)(ws + OFF_EMF);
    const float* emb = (const float*)(ws + OFF_EMB);
    char* bp = ws + OFF_BP;
    int*  lt = (int*)(ws + OFF_LT);
    bool act = t < T;

    float trp[T];
    float mb = 0.0f;
    if (act) {
        #pragma unroll
        for (int p = 0; p < T; p++) trp[p] = trans[p * T + t];
        mb = mlpb[t];
    }
    float score = -1e30f;
    if (act) score = strans[t] + emf[(b * S) * T + t] + emb[(b * S) * T + t] + mb;

    for (int s = 1; s < S; s++) {
        float e = 0.0f;
        if (act) e = emf[(b * S + s) * T + t] + emb[(b * S + s) * T + t] + mb;
        float best = __shfl(score, 0, 64) + trp[0];
        int bpi = 0;
        #pragma unroll
        for (int p = 1; p < T; p++) {
            float cand = __shfl(score, p, 64) + trp[p];
            if (cand > best) { best = cand; bpi = p; }
        }
        int m = data[b * S + s] != 0;
        if (act) {
            score = m ? (best + e) : score;
            bp[((size_t)(s - 1) * B + b) * 16 + t] = (char)bpi;
        }
    }
    float fin = act ? score + etrans[t] : -1e30f;
    float bv = __shfl(fin, 0, 64);
    int bi = 0;
    #pragma unroll
    for (int p = 1; p < T; p++) {
        float v = __shfl(fin, p, 64);
        if (v > bv) { bv = v; bi = p; }
    }
    if (t == 0) { out[B * S + b] = bv; lt[b] = bi; }
}

/* Backtrack: thread = batch; bp row address is tag-independent -> pipelined loads */
__global__ __launch_bounds__(128) void k_back(const int* __restrict__ data, char* __restrict__ ws) {
    int b = threadIdx.x;
    const int4* bp4 = (const int4*)(ws + OFF_BP);
    const int*  lt  = (const int*)(ws + OFF_LT);
    int* pt = (int*)(ws + OFF_PT);
    int tag = lt[b];
    pt[(S - 1) * B + b] = tag;
    for (int p = S - 2; p >= 0; p--) {
        int4 r = bp4[(size_t)p * B + b];
        int m = data[b * S + p + 1] != 0;
        unsigned w = (unsigned)(tag < 8 ? (tag < 4 ? r.x : r.y) : r.z);
        int nt = (int)((w >> ((tag & 3) * 8)) & 0xff);
        tag = m ? nt : tag;
        pt[p * B + b] = tag;
    }
}

/* paths -> float output with mask zeroing */
__global__ __launch_bounds__(256) void k_fin(const int* __restrict__ data,
                                             float* __restrict__ out,
                                             const char* __restrict__ ws) {
    int tid = blockIdx.x * 256 + threadIdx.x;   /* 65536 */
    const int* pt = (const int*)(ws + OFF_PT);
    int b = tid >> 9, p = tid & 511;
    out[tid] = (data[tid] != 0) ? (float)pt[p * B + b] : 0.0f;
}

extern "C" void kernel_launch(void* const* d_in, const int* in_sizes, int n_in,
                              void* d_out, int out_size, void* d_ws, size_t ws_size,
                              hipStream_t stream) {
    const int*   data = (const int*)d_in[0];
    /* d_in[1] = mask (bool) — unused; mask == (data != 0) */
    const float* emb  = (const float*)d_in[2];
    const float* wihf = (const float*)d_in[3];
    const float* whhf = (const float*)d_in[4];
    const float* bf   = (const float*)d_in[5];
    const float* wihb = (const float*)d_in[6];
    const float* whhb = (const float*)d_in[7];
    const float* bb   = (const float*)d_in[8];
    const float* mlpW = (const float*)d_in[9];
    const float* mlpb = (const float*)d_in[10];
    const float* st   = (const float*)d_in[11];
    const float* tr   = (const float*)d_in[12];
    const float* et   = (const float*)d_in[13];
    float* out = (float*)d_out;
    char*  ws  = (char*)d_ws;

    hipLaunchKernelGGL(k_pemb, dim3(750),  dim3(256), 0, stream, emb, wihf, bf, wihb, bb, ws);
    hipLaunchKernelGGL(k_prep, dim3(328),  dim3(256), 0, stream, whhf, whhb, ws);
    hipLaunchKernelGGL(k_lstm, dim3(256),  dim3(512), 0, stream, data, whhf, whhb, mlpW, ws);
    hipLaunchKernelGGL(k_vit,  dim3(128),  dim3(64),  0, stream, data, st, tr, et, mlpb, out, ws);
    hipLaunchKernelGGL(k_back, dim3(1),    dim3(128), 0, stream, data, ws);
    hipLaunchKernelGGL(k_fin,  dim3(256),  dim3(256), 0, stream, data, out, ws);
}